// Round 1
// baseline (11562.776 us; speedup 1.0000x reference)
//
#include <hip/hip_runtime.h>

#define NODES 32768
#define EDGES 524288
#define BGR   64
#define LSEQ  512
#define DEMB  256
#define HDIM  512

typedef unsigned short u16;
typedef unsigned int   u32;
typedef unsigned long long u64;
typedef __attribute__((ext_vector_type(8))) short short8;
typedef __attribute__((ext_vector_type(4))) float f32x4;

__device__ __forceinline__ float bf2f(u16 u){ u32 x = ((u32)u)<<16; float f; __builtin_memcpy(&f,&x,4); return f; }
__device__ __forceinline__ u16 f2bf(float f){ u32 x; __builtin_memcpy(&x,&f,4); u32 r = x + 0x7fffu + ((x>>16)&1u); return (u16)(r>>16); }
__device__ __forceinline__ float lo16(u32 u){ u32 x = u<<16; float f; __builtin_memcpy(&f,&x,4); return f; }
__device__ __forceinline__ float hi16(u32 u){ u32 x = u & 0xffff0000u; float f; __builtin_memcpy(&f,&x,4); return f; }
__device__ __forceinline__ u32 pack2(float a, float b){ return (u32)f2bf(a) | ((u32)f2bf(b)<<16); }

// ---------------- utility kernels ----------------

__global__ void zero_i32(int* p, int n){
  int i = blockIdx.x*256 + threadIdx.x;
  if (i < n) p[i] = 0;
}

// out[n*K + k] = bf16(in[k*N + n])   (in is [K][N] row-major)
__global__ void transpose_cast(const float* __restrict__ in, u16* __restrict__ out, int K, int N){
  int i = blockIdx.x*256 + threadIdx.x;
  if (i < N*K){ int n = i / K, k = i - n*K; out[i] = f2bf(in[(size_t)k*N + n]); }
}

__global__ void cast_bf(const float* __restrict__ in, u16* __restrict__ out, int n){
  int i = blockIdx.x*256 + threadIdx.x;
  if (i < n) out[i] = f2bf(in[i]);
}

__global__ void count_indeg(const int* __restrict__ dst, int* __restrict__ indeg){
  int e = blockIdx.x*256 + threadIdx.x;
  if (e < EDGES) atomicAdd(&indeg[dst[e]], 1);
}

__global__ void compute_dinv(const int* __restrict__ indeg, float* __restrict__ dinv){
  int i = blockIdx.x*256 + threadIdx.x;
  if (i < NODES) dinv[i] = rsqrtf((float)(indeg[i] + 1));  // +1 self loop
}

// single-block exclusive scan of indeg -> row_ptr (+cursor copy). N = 32768 = 1024*32
__global__ __launch_bounds__(1024) void scan_csr(const int* __restrict__ indeg,
                                                 int* __restrict__ row_ptr,
                                                 int* __restrict__ cursor){
  __shared__ int part[1024];
  int tid = threadIdx.x, base = tid*32;
  int loc[32]; int s = 0;
  for (int i=0;i<32;i++){ loc[i] = s; s += indeg[base+i]; }
  part[tid] = s; __syncthreads();
  for (int off=1; off<1024; off<<=1){
    int v = part[tid]; int add = (tid>=off) ? part[tid-off] : 0;
    __syncthreads(); part[tid] = v + add; __syncthreads();
  }
  int offt = (tid==0) ? 0 : part[tid-1];
  for (int i=0;i<32;i++){ int v = offt + loc[i]; row_ptr[base+i] = v; cursor[base+i] = v; }
}

__global__ void fill_csr(const int* __restrict__ src, const int* __restrict__ dst,
                         int* __restrict__ cursor, int* __restrict__ csr_src){
  int e = blockIdx.x*256 + threadIdx.x;
  if (e < EDGES){ int d = dst[e]; int p = atomicAdd(&cursor[d], 1); csr_src[p] = src[e]; }
}

// ---------------- GCN aggregation ----------------
// agg[i] = dinv[i] * ( dinv[i]*emb[x[i]] + sum_edges dinv[s]*emb[x[s]] )   (D=256, fp32 in, bf16 out)
__global__ __launch_bounds__(256) void agg_emb(const int* __restrict__ x, const float* __restrict__ emb,
    const float* __restrict__ dinv, const int* __restrict__ row_ptr, const int* __restrict__ indeg,
    const int* __restrict__ csr_src, u16* __restrict__ out){
  int node = blockIdx.x*4 + (threadIdx.x>>6);
  int lane = threadIdx.x & 63;
  float di = dinv[node];
  int xi = x[node];
  f32x4 acc = ((const f32x4*)(emb + (size_t)xi*DEMB))[lane] * di;
  int st = row_ptr[node], cn = indeg[node];
  for (int p = st; p < st+cn; p++){
    int s = csr_src[p];
    float ws = dinv[s];
    int xs = x[s];
    acc += ((const f32x4*)(emb + (size_t)xs*DEMB))[lane] * ws;
  }
  acc *= di;
  u64 pv = (u64)pack2(acc[0],acc[1]) | ((u64)pack2(acc[2],acc[3])<<32);
  *(u64*)(out + (size_t)node*DEMB + lane*4) = pv;
}

// same but H=512, bf16 input rows
__global__ __launch_bounds__(256) void agg_h(const u16* __restrict__ hin, const float* __restrict__ dinv,
    const int* __restrict__ row_ptr, const int* __restrict__ indeg,
    const int* __restrict__ csr_src, u16* __restrict__ out){
  int node = blockIdx.x*4 + (threadIdx.x>>6);
  int lane = threadIdx.x & 63;
  float di = dinv[node];
  float a[8];
  uint4 hv = *((const uint4*)(hin + (size_t)node*HDIM) + lane);
  a[0]=lo16(hv.x)*di; a[1]=hi16(hv.x)*di; a[2]=lo16(hv.y)*di; a[3]=hi16(hv.y)*di;
  a[4]=lo16(hv.z)*di; a[5]=hi16(hv.z)*di; a[6]=lo16(hv.w)*di; a[7]=hi16(hv.w)*di;
  int st = row_ptr[node], cn = indeg[node];
  for (int p = st; p < st+cn; p++){
    int s = csr_src[p];
    float ws = dinv[s];
    uint4 v = *((const uint4*)(hin + (size_t)s*HDIM) + lane);
    a[0]+=lo16(v.x)*ws; a[1]+=hi16(v.x)*ws; a[2]+=lo16(v.y)*ws; a[3]+=hi16(v.y)*ws;
    a[4]+=lo16(v.z)*ws; a[5]+=hi16(v.z)*ws; a[6]+=lo16(v.w)*ws; a[7]+=hi16(v.w)*ws;
  }
  uint4 o; o.x=pack2(a[0]*di,a[1]*di); o.y=pack2(a[2]*di,a[3]*di);
  o.z=pack2(a[4]*di,a[5]*di); o.w=pack2(a[6]*di,a[7]*di);
  *(uint4*)(out + (size_t)node*HDIM + lane*8) = o;
}

// ---------------- bf16 MFMA GEMM: C[M,N] = act(A[M,K] @ BT[N,K]^T + bias) ----------------
#define BM 128
#define BN 128
#define BKK 32
__global__ __launch_bounds__(256) void gemm_bt(const u16* __restrict__ A, const u16* __restrict__ BT,
    const float* __restrict__ bias, u16* __restrict__ C, int M, int N, int K, int relu){
  __shared__ u16 aS[BM][BKK+8];
  __shared__ u16 bS[BN][BKK+8];
  int tid = threadIdx.x;
  int m0 = blockIdx.y * BM, n0 = blockIdx.x * BN;
  int lane = tid & 63, w = tid >> 6;
  int wm = w >> 1, wn = w & 1;
  f32x4 acc[4][4];
  for (int i=0;i<4;i++) for (int j=0;j<4;j++) acc[i][j] = (f32x4)0.0f;

  int r  = tid >> 1;
  int cc = (tid & 1) * 16;
  const u16* Ag = A + (size_t)(m0 + r) * K + cc;
  const u16* Bg = BT + (size_t)(n0 + r) * K + cc;
  int l15 = lane & 15, q8 = (lane >> 4) * 8;

  for (int k0 = 0; k0 < K; k0 += BKK) {
    uint4 av0 = *(const uint4*)(Ag + k0);
    uint4 av1 = *(const uint4*)(Ag + k0 + 8);
    uint4 bv0 = *(const uint4*)(Bg + k0);
    uint4 bv1 = *(const uint4*)(Bg + k0 + 8);
    *(uint4*)&aS[r][cc]   = av0; *(uint4*)&aS[r][cc+8] = av1;
    *(uint4*)&bS[r][cc]   = bv0; *(uint4*)&bS[r][cc+8] = bv1;
    __syncthreads();
    short8 af[4], bfr[4];
    for (int i=0;i<4;i++) af[i]  = *(const short8*)&aS[wm*64 + i*16 + l15][q8];
    for (int j=0;j<4;j++) bfr[j] = *(const short8*)&bS[wn*64 + j*16 + l15][q8];
    for (int i=0;i<4;i++)
      for (int j=0;j<4;j++)
        acc[i][j] = __builtin_amdgcn_mfma_f32_16x16x32_bf16(af[i], bfr[j], acc[i][j], 0, 0, 0);
    __syncthreads();
  }
  int q = lane >> 4;
  for (int i=0;i<4;i++) for (int j=0;j<4;j++){
    int col = n0 + wn*64 + j*16 + l15;
    float bval = bias[col];
    for (int rr=0; rr<4; rr++){
      int row = m0 + wm*64 + i*16 + q*4 + rr;
      float v = acc[i][j][rr] + bval;
      if (relu) v = fmaxf(v, 0.f);
      C[(size_t)row * N + col] = f2bf(v);
    }
  }
}

// ---------------- GRU: 4 groups x 16 WGs; WG j owns 32-wide H-slice (96 Whh rows LDS-resident) ----------------
__global__ __launch_bounds__(512) void gru_kernel(const u16* __restrict__ gi,
    const float* __restrict__ Whh, const float* __restrict__ bhh,
    float* __restrict__ graph_emb, u16* __restrict__ xbuf, int* __restrict__ cnt){
  __shared__ u16  w_lds[96*520];
  __shared__ u16  h_lds[16*520];
  __shared__ float gh_lds[16*100];

  int tid = threadIdx.x;
  int g = blockIdx.x >> 4, j = blockIdx.x & 15;
  int lane = tid & 63, wave = tid >> 6;

  // load Whh slice: rows {j*32..+32} of each gate, bf16 into LDS (padded stride 520)
  for (int idx = tid; idx < 96*512; idx += 512){
    int rr = idx >> 9, c = idx & 511;
    int grow = (rr >> 5) * 512 + j*32 + (rr & 31);
    w_lds[rr*520 + c] = f2bf(Whh[(size_t)grow*512 + c]);
  }
  for (int idx = tid; idx < 16*520; idx += 512) h_lds[idx] = 0;

  int b = tid >> 5, hh = tid & 31;     // (batch-in-group, h-in-slice)
  int bg = g*16 + b;
  int c_r = j*32 + hh, c_z = 512 + j*32 + hh, c_n = 1024 + j*32 + hh;
  float bias_r = bhh[c_r], bias_z = bhh[c_z], bias_n = bhh[c_n];
  const u16* gi_row = gi + (size_t)bg * LSEQ * 1536;
  float h_prev = 0.f, accm = 0.f;
  int l15 = lane & 15, q8 = (lane>>4)*8, qr = (lane>>4)*4;

  __syncthreads();

  for (int t = 0; t < LSEQ; t++){
    const u16* gp = gi_row + (size_t)t * 1536;
    u16 g_r = gp[c_r], g_z = gp[c_z], g_n = gp[c_n];   // prefetch (indep of h)

    if (wave < 6){
      f32x4 acc = (f32x4)0.0f;
      const u16* wrow = &w_lds[(wave*16 + l15)*520];
      const u16* hrow = &h_lds[l15*520];
      #pragma unroll
      for (int k0 = 0; k0 < 512; k0 += 32){
        short8 af = *(const short8*)(hrow + k0 + q8);
        short8 bf = *(const short8*)(wrow + k0 + q8);
        acc = __builtin_amdgcn_mfma_f32_16x16x32_bf16(af, bf, acc, 0, 0, 0);
      }
      int col = wave*16 + l15;
      #pragma unroll
      for (int rr2 = 0; rr2 < 4; rr2++) gh_lds[(qr + rr2)*100 + col] = acc[rr2];
    }
    __syncthreads();

    float ghr = gh_lds[b*100 + hh]      + bias_r;
    float ghz = gh_lds[b*100 + 32 + hh] + bias_z;
    float ghn = gh_lds[b*100 + 64 + hh] + bias_n;
    float rg = 1.f / (1.f + __expf(-(bf2f(g_r) + ghr)));
    float zg = 1.f / (1.f + __expf(-(bf2f(g_z) + ghz)));
    float pre = bf2f(g_n) + rg * ghn;
    pre = fminf(fmaxf(pre, -20.f), 20.f);
    float e2 = __expf(2.f * pre);
    float nn = (e2 - 1.f) / (e2 + 1.f);
    float h_new = (1.f - zg) * nn + zg * h_prev;
    accm += h_new; h_prev = h_new;
    xbuf[((size_t)(g*2 + (t&1))*16 + b)*512 + j*32 + hh] = f2bf(h_new);

    __threadfence();
    __syncthreads();
    if (tid == 0){
      __hip_atomic_fetch_add(&cnt[g], 1, __ATOMIC_RELEASE, __HIP_MEMORY_SCOPE_AGENT);
      int target = 16*(t+1);
      while (__hip_atomic_load(&cnt[g], __ATOMIC_ACQUIRE, __HIP_MEMORY_SCOPE_AGENT) < target)
        __builtin_amdgcn_s_sleep(1);
    }
    __syncthreads();
    __threadfence();  // acquire: invalidate stale caches before reading peers' slices

    u64* src = (u64*)(xbuf + (size_t)(g*2 + (t&1))*16*512);
    for (int u = tid; u < 2048; u += 512){
      u64 v = __hip_atomic_load(src + u, __ATOMIC_RELAXED, __HIP_MEMORY_SCOPE_AGENT);
      *(u64*)&h_lds[(u >> 7)*520 + (u & 127)*4] = v;
    }
    __syncthreads();
  }
  graph_emb[(size_t)bg*512 + j*32 + hh] = accm * (1.f/512.f);
}

// ---------------- head: relu(g@fc1+b) @ fc2 + b -> sigmoid ----------------
__global__ __launch_bounds__(256) void head(const float* __restrict__ graph_emb, const float* __restrict__ focal,
    const float* __restrict__ fc1w, const float* __restrict__ fc1b,
    const float* __restrict__ fc2w, const float* __restrict__ fc2b, float* __restrict__ out){
  __shared__ float gv[513];
  __shared__ float h1s[512];
  __shared__ float red[4];
  int bq = blockIdx.x, tid = threadIdx.x;
  for (int i = tid; i < 512; i += 256) gv[i] = graph_emb[(size_t)bq*512 + i];
  if (tid == 0) gv[512] = focal[bq];
  __syncthreads();
  for (int c = tid; c < 512; c += 256){
    float acc = fc1b[c];
    for (int k = 0; k < 513; k++) acc += gv[k] * fc1w[(size_t)k*512 + c];
    h1s[c] = fmaxf(acc, 0.f);
  }
  __syncthreads();
  float p = h1s[tid]*fc2w[tid] + h1s[tid+256]*fc2w[tid+256];
  for (int off = 32; off; off >>= 1) p += __shfl_down(p, off, 64);
  if ((tid & 63) == 0) red[tid >> 6] = p;
  __syncthreads();
  if (tid == 0){
    float s = red[0]+red[1]+red[2]+red[3] + fc2b[0];
    out[bq] = 1.f / (1.f + __expf(-s));
  }
}

// ---------------- launch ----------------
extern "C" void kernel_launch(void* const* d_in, const int* in_sizes, int n_in,
                              void* d_out, int out_size, void* d_ws, size_t ws_size,
                              hipStream_t stream){
  const int*   x     = (const int*)d_in[0];
  const int*   edge  = (const int*)d_in[1];
  const int*   srcp  = edge;
  const int*   dstp  = edge + EDGES;
  const float* focal = (const float*)d_in[3];
  const float* emb   = (const float*)d_in[4];
  const float* W1    = (const float*)d_in[5];
  const float* b1    = (const float*)d_in[6];
  const float* W2    = (const float*)d_in[7];
  const float* b2    = (const float*)d_in[8];
  const float* Wih   = (const float*)d_in[9];
  const float* Whh   = (const float*)d_in[10];
  const float* bih   = (const float*)d_in[11];
  const float* bhh   = (const float*)d_in[12];
  const float* fc1w  = (const float*)d_in[13];
  const float* fc1b  = (const float*)d_in[14];
  const float* fc2w  = (const float*)d_in[15];
  const float* fc2b  = (const float*)d_in[16];

  char* ws = (char*)d_ws;
  // big bf16 buffers (gi overlaps the dead agg1/h1/agg2 region)
  constexpr size_t H2_OFF    = 0;                      // 32 MB
  constexpr size_t AGG1_OFF  = 33554432;               // 16 MB
  constexpr size_t H1_OFF    = 50331648;               // 32 MB
  constexpr size_t AGG2_OFF  = 83886080;               // 32 MB
  constexpr size_t GI_OFF    = 33554432;               // 96 MB (after aggs dead)
  constexpr size_t MISC      = 134217728;
  constexpr size_t INDEG_OFF = MISC;
  constexpr size_t CNT_OFF   = MISC + 131072;
  constexpr size_t DINV_OFF  = MISC + 131328;
  constexpr size_t ROWPTR_OFF= MISC + 262400;
  constexpr size_t CURSOR_OFF= MISC + 393472;
  constexpr size_t CSR_OFF   = MISC + 524544;
  constexpr size_t W1T_OFF   = MISC + 2621696;
  constexpr size_t W2T_OFF   = MISC + 2883840;
  constexpr size_t WIHB_OFF  = MISC + 3408128;
  constexpr size_t XBUF_OFF  = MISC + 4980992;
  constexpr size_t GEMB_OFF  = MISC + 5112064;

  int*   indeg  = (int*)(ws + INDEG_OFF);
  int*   cntp   = (int*)(ws + CNT_OFF);
  float* dinv   = (float*)(ws + DINV_OFF);
  int*   rowptr = (int*)(ws + ROWPTR_OFF);
  int*   cursor = (int*)(ws + CURSOR_OFF);
  int*   csrsrc = (int*)(ws + CSR_OFF);
  u16*   W1T    = (u16*)(ws + W1T_OFF);
  u16*   W2T    = (u16*)(ws + W2T_OFF);
  u16*   WihB   = (u16*)(ws + WIHB_OFF);
  u16*   agg1   = (u16*)(ws + AGG1_OFF);
  u16*   h1     = (u16*)(ws + H1_OFF);
  u16*   agg2   = (u16*)(ws + AGG2_OFF);
  u16*   h2     = (u16*)(ws + H2_OFF);
  u16*   gi     = (u16*)(ws + GI_OFF);
  u16*   xbuf   = (u16*)(ws + XBUF_OFF);
  float* gemb   = (float*)(ws + GEMB_OFF);

  zero_i32<<<129, 256, 0, stream>>>(indeg, 32768 + 64);   // indeg + cnt
  transpose_cast<<<512, 256, 0, stream>>>(W1, W1T, 256, 512);
  transpose_cast<<<1024, 256, 0, stream>>>(W2, W2T, 512, 512);
  cast_bf<<<3072, 256, 0, stream>>>(Wih, WihB, 1536*512);
  count_indeg<<<2048, 256, 0, stream>>>(dstp, indeg);
  compute_dinv<<<128, 256, 0, stream>>>(indeg, dinv);
  scan_csr<<<1, 1024, 0, stream>>>(indeg, rowptr, cursor);
  fill_csr<<<2048, 256, 0, stream>>>(srcp, dstp, cursor, csrsrc);
  agg_emb<<<8192, 256, 0, stream>>>(x, emb, dinv, rowptr, indeg, csrsrc, agg1);
  gemm_bt<<<dim3(4, 256), 256, 0, stream>>>(agg1, W1T, b1, h1, NODES, 512, 256, 1);
  agg_h<<<8192, 256, 0, stream>>>(h1, dinv, rowptr, indeg, csrsrc, agg2);
  gemm_bt<<<dim3(4, 256), 256, 0, stream>>>(agg2, W2T, b2, h2, NODES, 512, 512, 1);
  gemm_bt<<<dim3(12, 256), 256, 0, stream>>>(h2, WihB, bih, gi, NODES, 1536, 512, 0);
  gru_kernel<<<64, 512, 0, stream>>>(gi, Whh, bhh, gemb, xbuf, cntp);
  head<<<64, 256, 0, stream>>>(gemb, focal, fc1w, fc1b, fc2w, fc2b, (float*)d_out);
}

// Round 2
// 2895.654 us; speedup vs baseline: 3.9931x; 3.9931x over previous
//
#include <hip/hip_runtime.h>

#define NODES 32768
#define EDGES 524288
#define BGR   64
#define LSEQ  512
#define DEMB  256
#define HDIM  512

typedef unsigned short u16;
typedef unsigned int   u32;
typedef unsigned long long u64;
typedef __attribute__((ext_vector_type(8))) short short8;
typedef __attribute__((ext_vector_type(4))) float f32x4;

__device__ __forceinline__ float bf2f(u16 u){ u32 x = ((u32)u)<<16; float f; __builtin_memcpy(&f,&x,4); return f; }
__device__ __forceinline__ u16 f2bf(float f){ u32 x; __builtin_memcpy(&x,&f,4); u32 r = x + 0x7fffu + ((x>>16)&1u); return (u16)(r>>16); }
__device__ __forceinline__ float lo16(u32 u){ u32 x = u<<16; float f; __builtin_memcpy(&f,&x,4); return f; }
__device__ __forceinline__ float hi16(u32 u){ u32 x = u & 0xffff0000u; float f; __builtin_memcpy(&f,&x,4); return f; }
__device__ __forceinline__ u32 pack2(float a, float b){ return (u32)f2bf(a) | ((u32)f2bf(b)<<16); }

// ---------------- utility kernels ----------------

__global__ void zero_i32(int* p, int n){
  int i = blockIdx.x*256 + threadIdx.x;
  if (i < n) p[i] = 0;
}

// out[n*K + k] = bf16(in[k*N + n])   (in is [K][N] row-major)
__global__ void transpose_cast(const float* __restrict__ in, u16* __restrict__ out, int K, int N){
  int i = blockIdx.x*256 + threadIdx.x;
  if (i < N*K){ int n = i / K, k = i - n*K; out[i] = f2bf(in[(size_t)k*N + n]); }
}

__global__ void cast_bf(const float* __restrict__ in, u16* __restrict__ out, int n){
  int i = blockIdx.x*256 + threadIdx.x;
  if (i < n) out[i] = f2bf(in[i]);
}

__global__ void count_indeg(const int* __restrict__ dst, int* __restrict__ indeg){
  int e = blockIdx.x*256 + threadIdx.x;
  if (e < EDGES) atomicAdd(&indeg[dst[e]], 1);
}

__global__ void compute_dinv(const int* __restrict__ indeg, float* __restrict__ dinv){
  int i = blockIdx.x*256 + threadIdx.x;
  if (i < NODES) dinv[i] = rsqrtf((float)(indeg[i] + 1));  // +1 self loop
}

// single-block exclusive scan of indeg -> row_ptr (+cursor copy). N = 32768 = 1024*32
__global__ __launch_bounds__(1024) void scan_csr(const int* __restrict__ indeg,
                                                 int* __restrict__ row_ptr,
                                                 int* __restrict__ cursor){
  __shared__ int part[1024];
  int tid = threadIdx.x, base = tid*32;
  int loc[32]; int s = 0;
  for (int i=0;i<32;i++){ loc[i] = s; s += indeg[base+i]; }
  part[tid] = s; __syncthreads();
  for (int off=1; off<1024; off<<=1){
    int v = part[tid]; int add = (tid>=off) ? part[tid-off] : 0;
    __syncthreads(); part[tid] = v + add; __syncthreads();
  }
  int offt = (tid==0) ? 0 : part[tid-1];
  for (int i=0;i<32;i++){ int v = offt + loc[i]; row_ptr[base+i] = v; cursor[base+i] = v; }
}

__global__ void fill_csr(const int* __restrict__ src, const int* __restrict__ dst,
                         int* __restrict__ cursor, int* __restrict__ csr_src){
  int e = blockIdx.x*256 + threadIdx.x;
  if (e < EDGES){ int d = dst[e]; int p = atomicAdd(&cursor[d], 1); csr_src[p] = src[e]; }
}

// ---------------- GCN aggregation ----------------
__global__ __launch_bounds__(256) void agg_emb(const int* __restrict__ x, const float* __restrict__ emb,
    const float* __restrict__ dinv, const int* __restrict__ row_ptr, const int* __restrict__ indeg,
    const int* __restrict__ csr_src, u16* __restrict__ out){
  int node = blockIdx.x*4 + (threadIdx.x>>6);
  int lane = threadIdx.x & 63;
  float di = dinv[node];
  int xi = x[node];
  f32x4 acc = ((const f32x4*)(emb + (size_t)xi*DEMB))[lane] * di;
  int st = row_ptr[node], cn = indeg[node];
  for (int p = st; p < st+cn; p++){
    int s = csr_src[p];
    float ws = dinv[s];
    int xs = x[s];
    acc += ((const f32x4*)(emb + (size_t)xs*DEMB))[lane] * ws;
  }
  acc *= di;
  u64 pv = (u64)pack2(acc[0],acc[1]) | ((u64)pack2(acc[2],acc[3])<<32);
  *(u64*)(out + (size_t)node*DEMB + lane*4) = pv;
}

__global__ __launch_bounds__(256) void agg_h(const u16* __restrict__ hin, const float* __restrict__ dinv,
    const int* __restrict__ row_ptr, const int* __restrict__ indeg,
    const int* __restrict__ csr_src, u16* __restrict__ out){
  int node = blockIdx.x*4 + (threadIdx.x>>6);
  int lane = threadIdx.x & 63;
  float di = dinv[node];
  float a[8];
  uint4 hv = *((const uint4*)(hin + (size_t)node*HDIM) + lane);
  a[0]=lo16(hv.x)*di; a[1]=hi16(hv.x)*di; a[2]=lo16(hv.y)*di; a[3]=hi16(hv.y)*di;
  a[4]=lo16(hv.z)*di; a[5]=hi16(hv.z)*di; a[6]=lo16(hv.w)*di; a[7]=hi16(hv.w)*di;
  int st = row_ptr[node], cn = indeg[node];
  for (int p = st; p < st+cn; p++){
    int s = csr_src[p];
    float ws = dinv[s];
    uint4 v = *((const uint4*)(hin + (size_t)s*HDIM) + lane);
    a[0]+=lo16(v.x)*ws; a[1]+=hi16(v.x)*ws; a[2]+=lo16(v.y)*ws; a[3]+=hi16(v.y)*ws;
    a[4]+=lo16(v.z)*ws; a[5]+=hi16(v.z)*ws; a[6]+=lo16(v.w)*ws; a[7]+=hi16(v.w)*ws;
  }
  uint4 o; o.x=pack2(a[0]*di,a[1]*di); o.y=pack2(a[2]*di,a[3]*di);
  o.z=pack2(a[4]*di,a[5]*di); o.w=pack2(a[6]*di,a[7]*di);
  *(uint4*)(out + (size_t)node*HDIM + lane*8) = o;
}

// ---------------- bf16 MFMA GEMM: C[M,N] = act(A[M,K] @ BT[N,K]^T + bias) ----------------
#define BM 128
#define BN 128
#define BKK 32
__global__ __launch_bounds__(256) void gemm_bt(const u16* __restrict__ A, const u16* __restrict__ BT,
    const float* __restrict__ bias, u16* __restrict__ C, int M, int N, int K, int relu){
  __shared__ u16 aS[BM][BKK+8];
  __shared__ u16 bS[BN][BKK+8];
  int tid = threadIdx.x;
  int m0 = blockIdx.y * BM, n0 = blockIdx.x * BN;
  int lane = tid & 63, w = tid >> 6;
  int wm = w >> 1, wn = w & 1;
  f32x4 acc[4][4];
  for (int i=0;i<4;i++) for (int j=0;j<4;j++) acc[i][j] = (f32x4)0.0f;

  int r  = tid >> 1;
  int cc = (tid & 1) * 16;
  const u16* Ag = A + (size_t)(m0 + r) * K + cc;
  const u16* Bg = BT + (size_t)(n0 + r) * K + cc;
  int l15 = lane & 15, q8 = (lane >> 4) * 8;

  for (int k0 = 0; k0 < K; k0 += BKK) {
    uint4 av0 = *(const uint4*)(Ag + k0);
    uint4 av1 = *(const uint4*)(Ag + k0 + 8);
    uint4 bv0 = *(const uint4*)(Bg + k0);
    uint4 bv1 = *(const uint4*)(Bg + k0 + 8);
    *(uint4*)&aS[r][cc]   = av0; *(uint4*)&aS[r][cc+8] = av1;
    *(uint4*)&bS[r][cc]   = bv0; *(uint4*)&bS[r][cc+8] = bv1;
    __syncthreads();
    short8 af[4], bfr[4];
    for (int i=0;i<4;i++) af[i]  = *(const short8*)&aS[wm*64 + i*16 + l15][q8];
    for (int j=0;j<4;j++) bfr[j] = *(const short8*)&bS[wn*64 + j*16 + l15][q8];
    for (int i=0;i<4;i++)
      for (int j=0;j<4;j++)
        acc[i][j] = __builtin_amdgcn_mfma_f32_16x16x32_bf16(af[i], bfr[j], acc[i][j], 0, 0, 0);
    __syncthreads();
  }
  int q = lane >> 4;
  for (int i=0;i<4;i++) for (int j=0;j<4;j++){
    int col = n0 + wn*64 + j*16 + l15;
    float bval = bias[col];
    for (int rr=0; rr<4; rr++){
      int row = m0 + wm*64 + i*16 + q*4 + rr;
      float v = acc[i][j][rr] + bval;
      if (relu) v = fmaxf(v, 0.f);
      C[(size_t)row * N + col] = f2bf(v);
    }
  }
}

// ---------------- GRU: 4 groups x 16 WGs; WG j owns 32-wide H-slice (96 Whh rows LDS-resident) ----------------
// Sync protocol: NO fences (agent-scope fence = full L2 wb/inv = ~10us/step, R1 killer).
// All cross-WG data moves via relaxed AGENT-scope atomics (coherence point = Infinity Cache,
// bypasses non-coherent XCD L2). Ordering: s_waitcnt vmcnt(0) before the counter bump.
__global__ __launch_bounds__(512) void gru_kernel(const u16* __restrict__ gi,
    const float* __restrict__ Whh, const float* __restrict__ bhh,
    float* __restrict__ graph_emb, u16* __restrict__ xbuf, int* __restrict__ cnt){
  __shared__ u16  w_lds[96*520];
  __shared__ u16  h_lds[16*520];
  __shared__ float gh_lds[16*100];

  int tid = threadIdx.x;
  int g = blockIdx.x >> 4, j = blockIdx.x & 15;
  int lane = tid & 63, wave = tid >> 6;

  // load Whh slice: rows {j*32..+32} of each gate, bf16 into LDS (padded stride 520)
  for (int idx = tid; idx < 96*512; idx += 512){
    int rr = idx >> 9, c = idx & 511;
    int grow = (rr >> 5) * 512 + j*32 + (rr & 31);
    w_lds[rr*520 + c] = f2bf(Whh[(size_t)grow*512 + c]);
  }
  for (int idx = tid; idx < 16*520; idx += 512) h_lds[idx] = 0;

  int b = tid >> 5, hh = tid & 31;     // (batch-in-group, h-in-slice)
  int bg = g*16 + b;
  int c_r = j*32 + hh, c_z = 512 + j*32 + hh, c_n = 1024 + j*32 + hh;
  float bias_r = bhh[c_r], bias_z = bhh[c_z], bias_n = bhh[c_n];
  const u16* gi_row = gi + (size_t)bg * LSEQ * 1536;
  float h_prev = 0.f, accm = 0.f;
  int l15 = lane & 15, q8 = (lane>>4)*8, qr = (lane>>4)*4;

  u32* xbuf32 = (u32*)xbuf;

  __syncthreads();

  for (int t = 0; t < LSEQ; t++){
    const u16* gp = gi_row + (size_t)t * 1536;
    u16 g_r = gp[c_r], g_z = gp[c_z], g_n = gp[c_n];   // prefetch (indep of h)

    if (wave < 6){
      f32x4 acc = (f32x4)0.0f;
      const u16* wrow = &w_lds[(wave*16 + l15)*520];
      const u16* hrow = &h_lds[l15*520];
      #pragma unroll
      for (int k0 = 0; k0 < 512; k0 += 32){
        short8 af = *(const short8*)(hrow + k0 + q8);
        short8 bf = *(const short8*)(wrow + k0 + q8);
        acc = __builtin_amdgcn_mfma_f32_16x16x32_bf16(af, bf, acc, 0, 0, 0);
      }
      int col = wave*16 + l15;
      #pragma unroll
      for (int rr2 = 0; rr2 < 4; rr2++) gh_lds[(qr + rr2)*100 + col] = acc[rr2];
    }
    __syncthreads();

    float ghr = gh_lds[b*100 + hh]      + bias_r;
    float ghz = gh_lds[b*100 + 32 + hh] + bias_z;
    float ghn = gh_lds[b*100 + 64 + hh] + bias_n;
    float rg = 1.f / (1.f + __expf(-(bf2f(g_r) + ghr)));
    float zg = 1.f / (1.f + __expf(-(bf2f(g_z) + ghz)));
    float pre = bf2f(g_n) + rg * ghn;
    pre = fminf(fmaxf(pre, -20.f), 20.f);
    float e2 = __expf(2.f * pre);
    float nn = (e2 - 1.f) / (e2 + 1.f);
    float h_new = (1.f - zg) * nn + zg * h_prev;
    accm += h_new; h_prev = h_new;

    // publish h_t: pack bf16 pair, relaxed agent-scope atomic store (no fence needed)
    float h_nb = __shfl_xor(h_new, 1, 64);   // partner hh^1 (same wave: lane^1)
    if ((hh & 1) == 0){
      u32 pv = pack2(h_new, h_nb);
      u32* dst32 = xbuf32 + ((size_t)(g*2 + (t&1))*16 + b)*256 + ((j*32 + hh) >> 1);
      __hip_atomic_store(dst32, pv, __ATOMIC_RELAXED, __HIP_MEMORY_SCOPE_AGENT);
    }
    asm volatile("s_waitcnt vmcnt(0)" ::: "memory");  // stores retired at coherence point
    __syncthreads();
    if (tid == 0){
      __hip_atomic_fetch_add(&cnt[g], 1, __ATOMIC_RELAXED, __HIP_MEMORY_SCOPE_AGENT);
      int target = 16*(t+1);
      while (__hip_atomic_load(&cnt[g], __ATOMIC_RELAXED, __HIP_MEMORY_SCOPE_AGENT) < target)
        __builtin_amdgcn_s_sleep(1);
    }
    __syncthreads();

    // refill full h_t (all 16 slices) from coherence point
    u64* src = (u64*)(xbuf + (size_t)(g*2 + (t&1))*16*512);
    for (int u = tid; u < 2048; u += 512){
      u64 v = __hip_atomic_load(src + u, __ATOMIC_RELAXED, __HIP_MEMORY_SCOPE_AGENT);
      *(u64*)&h_lds[(u >> 7)*520 + (u & 127)*4] = v;
    }
    __syncthreads();
  }
  graph_emb[(size_t)bg*512 + j*32 + hh] = accm * (1.f/512.f);
}

// ---------------- head: relu(g@fc1+b) @ fc2 + b -> sigmoid ----------------
__global__ __launch_bounds__(256) void head(const float* __restrict__ graph_emb, const float* __restrict__ focal,
    const float* __restrict__ fc1w, const float* __restrict__ fc1b,
    const float* __restrict__ fc2w, const float* __restrict__ fc2b, float* __restrict__ out){
  __shared__ float gv[513];
  __shared__ float h1s[512];
  __shared__ float red[4];
  int bq = blockIdx.x, tid = threadIdx.x;
  for (int i = tid; i < 512; i += 256) gv[i] = graph_emb[(size_t)bq*512 + i];
  if (tid == 0) gv[512] = focal[bq];
  __syncthreads();
  for (int c = tid; c < 512; c += 256){
    float acc = fc1b[c];
    for (int k = 0; k < 513; k++) acc += gv[k] * fc1w[(size_t)k*512 + c];
    h1s[c] = fmaxf(acc, 0.f);
  }
  __syncthreads();
  float p = h1s[tid]*fc2w[tid] + h1s[tid+256]*fc2w[tid+256];
  for (int off = 32; off; off >>= 1) p += __shfl_down(p, off, 64);
  if ((tid & 63) == 0) red[tid >> 6] = p;
  __syncthreads();
  if (tid == 0){
    float s = red[0]+red[1]+red[2]+red[3] + fc2b[0];
    out[bq] = 1.f / (1.f + __expf(-s));
  }
}

// ---------------- launch ----------------
extern "C" void kernel_launch(void* const* d_in, const int* in_sizes, int n_in,
                              void* d_out, int out_size, void* d_ws, size_t ws_size,
                              hipStream_t stream){
  const int*   x     = (const int*)d_in[0];
  const int*   edge  = (const int*)d_in[1];
  const int*   srcp  = edge;
  const int*   dstp  = edge + EDGES;
  const float* focal = (const float*)d_in[3];
  const float* emb   = (const float*)d_in[4];
  const float* W1    = (const float*)d_in[5];
  const float* b1    = (const float*)d_in[6];
  const float* W2    = (const float*)d_in[7];
  const float* b2    = (const float*)d_in[8];
  const float* Wih   = (const float*)d_in[9];
  const float* Whh   = (const float*)d_in[10];
  const float* bih   = (const float*)d_in[11];
  const float* bhh   = (const float*)d_in[12];
  const float* fc1w  = (const float*)d_in[13];
  const float* fc1b  = (const float*)d_in[14];
  const float* fc2w  = (const float*)d_in[15];
  const float* fc2b  = (const float*)d_in[16];

  char* ws = (char*)d_ws;
  constexpr size_t H2_OFF    = 0;                      // 32 MB
  constexpr size_t AGG1_OFF  = 33554432;               // 16 MB
  constexpr size_t H1_OFF    = 50331648;               // 32 MB
  constexpr size_t AGG2_OFF  = 83886080;               // 32 MB
  constexpr size_t GI_OFF    = 33554432;               // 96 MB (after aggs dead)
  constexpr size_t MISC      = 134217728;
  constexpr size_t INDEG_OFF = MISC;
  constexpr size_t CNT_OFF   = MISC + 131072;
  constexpr size_t DINV_OFF  = MISC + 131328;
  constexpr size_t ROWPTR_OFF= MISC + 262400;
  constexpr size_t CURSOR_OFF= MISC + 393472;
  constexpr size_t CSR_OFF   = MISC + 524544;
  constexpr size_t W1T_OFF   = MISC + 2621696;
  constexpr size_t W2T_OFF   = MISC + 2883840;
  constexpr size_t WIHB_OFF  = MISC + 3408128;
  constexpr size_t XBUF_OFF  = MISC + 4980992;
  constexpr size_t GEMB_OFF  = MISC + 5112064;

  int*   indeg  = (int*)(ws + INDEG_OFF);
  int*   cntp   = (int*)(ws + CNT_OFF);
  float* dinv   = (float*)(ws + DINV_OFF);
  int*   rowptr = (int*)(ws + ROWPTR_OFF);
  int*   cursor = (int*)(ws + CURSOR_OFF);
  int*   csrsrc = (int*)(ws + CSR_OFF);
  u16*   W1T    = (u16*)(ws + W1T_OFF);
  u16*   W2T    = (u16*)(ws + W2T_OFF);
  u16*   WihB   = (u16*)(ws + WIHB_OFF);
  u16*   agg1   = (u16*)(ws + AGG1_OFF);
  u16*   h1     = (u16*)(ws + H1_OFF);
  u16*   agg2   = (u16*)(ws + AGG2_OFF);
  u16*   h2     = (u16*)(ws + H2_OFF);
  u16*   gi     = (u16*)(ws + GI_OFF);
  u16*   xbuf   = (u16*)(ws + XBUF_OFF);
  float* gemb   = (float*)(ws + GEMB_OFF);

  zero_i32<<<129, 256, 0, stream>>>(indeg, 32768 + 64);   // indeg + cnt
  transpose_cast<<<512, 256, 0, stream>>>(W1, W1T, 256, 512);
  transpose_cast<<<1024, 256, 0, stream>>>(W2, W2T, 512, 512);
  cast_bf<<<3072, 256, 0, stream>>>(Wih, WihB, 1536*512);
  count_indeg<<<2048, 256, 0, stream>>>(dstp, indeg);
  compute_dinv<<<128, 256, 0, stream>>>(indeg, dinv);
  scan_csr<<<1, 1024, 0, stream>>>(indeg, rowptr, cursor);
  fill_csr<<<2048, 256, 0, stream>>>(srcp, dstp, cursor, csrsrc);
  agg_emb<<<8192, 256, 0, stream>>>(x, emb, dinv, rowptr, indeg, csrsrc, agg1);
  gemm_bt<<<dim3(4, 256), 256, 0, stream>>>(agg1, W1T, b1, h1, NODES, 512, 256, 1);
  agg_h<<<8192, 256, 0, stream>>>(h1, dinv, rowptr, indeg, csrsrc, agg2);
  gemm_bt<<<dim3(4, 256), 256, 0, stream>>>(agg2, W2T, b2, h2, NODES, 512, 512, 1);
  gemm_bt<<<dim3(12, 256), 256, 0, stream>>>(h2, WihB, bih, gi, NODES, 1536, 512, 0);
  gru_kernel<<<64, 512, 0, stream>>>(gi, Whh, bhh, gemb, xbuf, cntp);
  head<<<64, 256, 0, stream>>>(gemb, focal, fc1w, fc1b, fc2w, fc2b, (float*)d_out);
}

// Round 3
// 2743.411 us; speedup vs baseline: 4.2147x; 1.0555x over previous
//
#include <hip/hip_runtime.h>

#define NODES 32768
#define EDGES 524288
#define BGR   64
#define LSEQ  512
#define DEMB  256
#define HDIM  512

typedef unsigned short u16;
typedef unsigned int   u32;
typedef unsigned long long u64;
typedef __attribute__((ext_vector_type(8))) short short8;
typedef __attribute__((ext_vector_type(4))) float f32x4;

__device__ __forceinline__ float bf2f(u16 u){ u32 x = ((u32)u)<<16; float f; __builtin_memcpy(&f,&x,4); return f; }
__device__ __forceinline__ u16 f2bf(float f){ u32 x; __builtin_memcpy(&x,&f,4); u32 r = x + 0x7fffu + ((x>>16)&1u); return (u16)(r>>16); }
__device__ __forceinline__ float lo16(u32 u){ u32 x = u<<16; float f; __builtin_memcpy(&f,&x,4); return f; }
__device__ __forceinline__ float hi16(u32 u){ u32 x = u & 0xffff0000u; float f; __builtin_memcpy(&f,&x,4); return f; }
__device__ __forceinline__ u32 pack2(float a, float b){ return (u32)f2bf(a) | ((u32)f2bf(b)<<16); }

// ---------------- utility kernels ----------------

__global__ void zero_i32(int* p, int n){
  int i = blockIdx.x*256 + threadIdx.x;
  if (i < n) p[i] = 0;
}

// out[n*K + k] = bf16(in[k*N + n])   (in is [K][N] row-major)
__global__ void transpose_cast(const float* __restrict__ in, u16* __restrict__ out, int K, int N){
  int i = blockIdx.x*256 + threadIdx.x;
  if (i < N*K){ int n = i / K, k = i - n*K; out[i] = f2bf(in[(size_t)k*N + n]); }
}

__global__ void cast_bf(const float* __restrict__ in, u16* __restrict__ out, int n){
  int i = blockIdx.x*256 + threadIdx.x;
  if (i < n) out[i] = f2bf(in[i]);
}

__global__ void count_indeg(const int* __restrict__ dst, int* __restrict__ indeg){
  int e = blockIdx.x*256 + threadIdx.x;
  if (e < EDGES) atomicAdd(&indeg[dst[e]], 1);
}

__global__ void compute_dinv(const int* __restrict__ indeg, float* __restrict__ dinv){
  int i = blockIdx.x*256 + threadIdx.x;
  if (i < NODES) dinv[i] = rsqrtf((float)(indeg[i] + 1));  // +1 self loop
}

// single-block exclusive scan of indeg -> row_ptr (+cursor copy). N = 32768 = 1024*32
__global__ __launch_bounds__(1024) void scan_csr(const int* __restrict__ indeg,
                                                 int* __restrict__ row_ptr,
                                                 int* __restrict__ cursor){
  __shared__ int part[1024];
  int tid = threadIdx.x, base = tid*32;
  int loc[32]; int s = 0;
  for (int i=0;i<32;i++){ loc[i] = s; s += indeg[base+i]; }
  part[tid] = s; __syncthreads();
  for (int off=1; off<1024; off<<=1){
    int v = part[tid]; int add = (tid>=off) ? part[tid-off] : 0;
    __syncthreads(); part[tid] = v + add; __syncthreads();
  }
  int offt = (tid==0) ? 0 : part[tid-1];
  for (int i=0;i<32;i++){ int v = offt + loc[i]; row_ptr[base+i] = v; cursor[base+i] = v; }
}

__global__ void fill_csr(const int* __restrict__ src, const int* __restrict__ dst,
                         int* __restrict__ cursor, int* __restrict__ csr_src){
  int e = blockIdx.x*256 + threadIdx.x;
  if (e < EDGES){ int d = dst[e]; int p = atomicAdd(&cursor[d], 1); csr_src[p] = src[e]; }
}

// ---------------- GCN aggregation ----------------
__global__ __launch_bounds__(256) void agg_emb(const int* __restrict__ x, const float* __restrict__ emb,
    const float* __restrict__ dinv, const int* __restrict__ row_ptr, const int* __restrict__ indeg,
    const int* __restrict__ csr_src, u16* __restrict__ out){
  int node = blockIdx.x*4 + (threadIdx.x>>6);
  int lane = threadIdx.x & 63;
  float di = dinv[node];
  int xi = x[node];
  f32x4 acc = ((const f32x4*)(emb + (size_t)xi*DEMB))[lane] * di;
  int st = row_ptr[node], cn = indeg[node];
  for (int p = st; p < st+cn; p++){
    int s = csr_src[p];
    float ws = dinv[s];
    int xs = x[s];
    acc += ((const f32x4*)(emb + (size_t)xs*DEMB))[lane] * ws;
  }
  acc *= di;
  u64 pv = (u64)pack2(acc[0],acc[1]) | ((u64)pack2(acc[2],acc[3])<<32);
  *(u64*)(out + (size_t)node*DEMB + lane*4) = pv;
}

__global__ __launch_bounds__(256) void agg_h(const u16* __restrict__ hin, const float* __restrict__ dinv,
    const int* __restrict__ row_ptr, const int* __restrict__ indeg,
    const int* __restrict__ csr_src, u16* __restrict__ out){
  int node = blockIdx.x*4 + (threadIdx.x>>6);
  int lane = threadIdx.x & 63;
  float di = dinv[node];
  float a[8];
  uint4 hv = *((const uint4*)(hin + (size_t)node*HDIM) + lane);
  a[0]=lo16(hv.x)*di; a[1]=hi16(hv.x)*di; a[2]=lo16(hv.y)*di; a[3]=hi16(hv.y)*di;
  a[4]=lo16(hv.z)*di; a[5]=hi16(hv.z)*di; a[6]=lo16(hv.w)*di; a[7]=hi16(hv.w)*di;
  int st = row_ptr[node], cn = indeg[node];
  for (int p = st; p < st+cn; p++){
    int s = csr_src[p];
    float ws = dinv[s];
    uint4 v = *((const uint4*)(hin + (size_t)s*HDIM) + lane);
    a[0]+=lo16(v.x)*ws; a[1]+=hi16(v.x)*ws; a[2]+=lo16(v.y)*ws; a[3]+=hi16(v.y)*ws;
    a[4]+=lo16(v.z)*ws; a[5]+=hi16(v.z)*ws; a[6]+=lo16(v.w)*ws; a[7]+=hi16(v.w)*ws;
  }
  uint4 o; o.x=pack2(a[0]*di,a[1]*di); o.y=pack2(a[2]*di,a[3]*di);
  o.z=pack2(a[4]*di,a[5]*di); o.w=pack2(a[6]*di,a[7]*di);
  *(uint4*)(out + (size_t)node*HDIM + lane*8) = o;
}

// ---------------- bf16 MFMA GEMM: C[M,N] = act(A[M,K] @ BT[N,K]^T + bias) ----------------
#define BM 128
#define BN 128
#define BKK 32
__global__ __launch_bounds__(256) void gemm_bt(const u16* __restrict__ A, const u16* __restrict__ BT,
    const float* __restrict__ bias, u16* __restrict__ C, int M, int N, int K, int relu){
  __shared__ u16 aS[BM][BKK+8];
  __shared__ u16 bS[BN][BKK+8];
  int tid = threadIdx.x;
  int m0 = blockIdx.y * BM, n0 = blockIdx.x * BN;
  int lane = tid & 63, w = tid >> 6;
  int wm = w >> 1, wn = w & 1;
  f32x4 acc[4][4];
  for (int i=0;i<4;i++) for (int j=0;j<4;j++) acc[i][j] = (f32x4)0.0f;

  int r  = tid >> 1;
  int cc = (tid & 1) * 16;
  const u16* Ag = A + (size_t)(m0 + r) * K + cc;
  const u16* Bg = BT + (size_t)(n0 + r) * K + cc;
  int l15 = lane & 15, q8 = (lane >> 4) * 8;

  for (int k0 = 0; k0 < K; k0 += BKK) {
    uint4 av0 = *(const uint4*)(Ag + k0);
    uint4 av1 = *(const uint4*)(Ag + k0 + 8);
    uint4 bv0 = *(const uint4*)(Bg + k0);
    uint4 bv1 = *(const uint4*)(Bg + k0 + 8);
    *(uint4*)&aS[r][cc]   = av0; *(uint4*)&aS[r][cc+8] = av1;
    *(uint4*)&bS[r][cc]   = bv0; *(uint4*)&bS[r][cc+8] = bv1;
    __syncthreads();
    short8 af[4], bfr[4];
    for (int i=0;i<4;i++) af[i]  = *(const short8*)&aS[wm*64 + i*16 + l15][q8];
    for (int j=0;j<4;j++) bfr[j] = *(const short8*)&bS[wn*64 + j*16 + l15][q8];
    for (int i=0;i<4;i++)
      for (int j=0;j<4;j++)
        acc[i][j] = __builtin_amdgcn_mfma_f32_16x16x32_bf16(af[i], bfr[j], acc[i][j], 0, 0, 0);
    __syncthreads();
  }
  int q = lane >> 4;
  for (int i=0;i<4;i++) for (int j=0;j<4;j++){
    int col = n0 + wn*64 + j*16 + l15;
    float bval = bias[col];
    for (int rr=0; rr<4; rr++){
      int row = m0 + wm*64 + i*16 + q*4 + rr;
      float v = acc[i][j][rr] + bval;
      if (relu) v = fmaxf(v, 0.f);
      C[(size_t)row * N + col] = f2bf(v);
    }
  }
}

// ---------------- GRU: 4 groups x 16 WGs; WG j owns 32-wide H-slice (96 Whh rows LDS-resident) ----------------
// Sync protocol: NO fences. All cross-WG data via relaxed AGENT-scope atomics (coherence point,
// bypasses non-coherent XCD L2). Ordering: s_waitcnt vmcnt(0) before the counter bump.
// R3: refill batched (4 loads in flight, 1 round trip instead of 4 serial); gi gate loads
// software-pipelined to overlap the counter poll; MFMA acc chain split in two.
__global__ __launch_bounds__(512) void gru_kernel(const u16* __restrict__ gi,
    const float* __restrict__ Whh, const float* __restrict__ bhh,
    float* __restrict__ graph_emb, u16* __restrict__ xbuf, int* __restrict__ cnt){
  __shared__ u16  w_lds[96*520];
  __shared__ u16  h_lds[16*520];
  __shared__ float gh_lds[16*100];

  int tid = threadIdx.x;
  int g = blockIdx.x >> 4, j = blockIdx.x & 15;
  int lane = tid & 63, wave = tid >> 6;

  // load Whh slice: rows {j*32..+32} of each gate, bf16 into LDS (padded stride 520)
  for (int idx = tid; idx < 96*512; idx += 512){
    int rr = idx >> 9, c = idx & 511;
    int grow = (rr >> 5) * 512 + j*32 + (rr & 31);
    w_lds[rr*520 + c] = f2bf(Whh[(size_t)grow*512 + c]);
  }
  for (int idx = tid; idx < 16*520; idx += 512) h_lds[idx] = 0;

  int b = tid >> 5, hh = tid & 31;     // (batch-in-group, h-in-slice)
  int bg = g*16 + b;
  int c_r = j*32 + hh, c_z = 512 + j*32 + hh, c_n = 1024 + j*32 + hh;
  float bias_r = bhh[c_r], bias_z = bhh[c_z], bias_n = bhh[c_n];
  const u16* gi_row = gi + (size_t)bg * LSEQ * 1536;
  float h_prev = 0.f, accm = 0.f;
  int l15 = lane & 15, q8 = (lane>>4)*8, qr = (lane>>4)*4;

  u32* xbuf32 = (u32*)xbuf;

  // refill LDS targets for the 4 batched u64 loads (u = tid + k*512)
  int ro0 = ((tid       ) >> 7)*520 + ((tid       ) & 127)*4;
  int ro1 = ((tid +  512) >> 7)*520 + ((tid +  512) & 127)*4;
  int ro2 = ((tid + 1024) >> 7)*520 + ((tid + 1024) & 127)*4;
  int ro3 = ((tid + 1536) >> 7)*520 + ((tid + 1536) & 127)*4;

  // pipeline: gate inputs for step t held in registers, loaded during step t-1's wait
  u16 g_r = gi_row[c_r], g_z = gi_row[c_z], g_n = gi_row[c_n];

  __syncthreads();

  for (int t = 0; t < LSEQ; t++){
    if (wave < 6){
      f32x4 acc0 = (f32x4)0.0f, acc1 = (f32x4)0.0f;
      const u16* wrow = &w_lds[(wave*16 + l15)*520];
      const u16* hrow = &h_lds[l15*520];
      #pragma unroll
      for (int k0 = 0; k0 < 256; k0 += 32){
        acc0 = __builtin_amdgcn_mfma_f32_16x16x32_bf16(*(const short8*)(hrow + k0 + q8),
                                                       *(const short8*)(wrow + k0 + q8), acc0, 0, 0, 0);
        acc1 = __builtin_amdgcn_mfma_f32_16x16x32_bf16(*(const short8*)(hrow + 256 + k0 + q8),
                                                       *(const short8*)(wrow + 256 + k0 + q8), acc1, 0, 0, 0);
      }
      f32x4 acc = acc0 + acc1;
      int col = wave*16 + l15;
      #pragma unroll
      for (int rr2 = 0; rr2 < 4; rr2++) gh_lds[(qr + rr2)*100 + col] = acc[rr2];
    }
    __syncthreads();

    float ghr = gh_lds[b*100 + hh]      + bias_r;
    float ghz = gh_lds[b*100 + 32 + hh] + bias_z;
    float ghn = gh_lds[b*100 + 64 + hh] + bias_n;
    float rg = 1.f / (1.f + __expf(-(bf2f(g_r) + ghr)));
    float zg = 1.f / (1.f + __expf(-(bf2f(g_z) + ghz)));
    float pre = bf2f(g_n) + rg * ghn;
    pre = fminf(fmaxf(pre, -20.f), 20.f);
    float e2 = __expf(2.f * pre);
    float nn = (e2 - 1.f) / (e2 + 1.f);
    float h_new = (1.f - zg) * nn + zg * h_prev;
    accm += h_new; h_prev = h_new;

    // publish h_t: pack bf16 pair, relaxed agent-scope atomic store
    float h_nb = __shfl_xor(h_new, 1, 64);   // partner hh^1 (same wave: lane^1)
    if ((hh & 1) == 0){
      u32 pv = pack2(h_new, h_nb);
      u32* dst32 = xbuf32 + ((size_t)(g*2 + (t&1))*16 + b)*256 + ((j*32 + hh) >> 1);
      __hip_atomic_store(dst32, pv, __ATOMIC_RELAXED, __HIP_MEMORY_SCOPE_AGENT);
    }
    asm volatile("s_waitcnt vmcnt(0)" ::: "memory");  // publish retired at coherence point

    // prefetch next step's gate inputs (overlaps poll + refill; consumed next iter)
    int tn = (t + 1 < LSEQ) ? t + 1 : t;
    const u16* gp = gi_row + (size_t)tn * 1536;
    u16 n_r = gp[c_r], n_z = gp[c_z], n_n = gp[c_n];

    __syncthreads();
    if (tid == 0){
      __hip_atomic_fetch_add(&cnt[g], 1, __ATOMIC_RELAXED, __HIP_MEMORY_SCOPE_AGENT);
      int target = 16*(t+1);
      while (__hip_atomic_load(&cnt[g], __ATOMIC_RELAXED, __HIP_MEMORY_SCOPE_AGENT) < target)
        __builtin_amdgcn_s_sleep(1);
    }
    __syncthreads();

    // refill full h_t: batch all 4 u64 agent loads (one pipelined round trip), then LDS writes
    u64* src = (u64*)(xbuf + (size_t)(g*2 + (t&1))*16*512);
    u64 r0 = __hip_atomic_load(src + tid,        __ATOMIC_RELAXED, __HIP_MEMORY_SCOPE_AGENT);
    u64 r1 = __hip_atomic_load(src + tid +  512, __ATOMIC_RELAXED, __HIP_MEMORY_SCOPE_AGENT);
    u64 r2 = __hip_atomic_load(src + tid + 1024, __ATOMIC_RELAXED, __HIP_MEMORY_SCOPE_AGENT);
    u64 r3 = __hip_atomic_load(src + tid + 1536, __ATOMIC_RELAXED, __HIP_MEMORY_SCOPE_AGENT);
    *(u64*)&h_lds[ro0] = r0;
    *(u64*)&h_lds[ro1] = r1;
    *(u64*)&h_lds[ro2] = r2;
    *(u64*)&h_lds[ro3] = r3;
    __syncthreads();

    g_r = n_r; g_z = n_z; g_n = n_n;
  }
  graph_emb[(size_t)bg*512 + j*32 + hh] = accm * (1.f/512.f);
}

// ---------------- head: relu(g@fc1+b) @ fc2 + b -> sigmoid ----------------
__global__ __launch_bounds__(256) void head(const float* __restrict__ graph_emb, const float* __restrict__ focal,
    const float* __restrict__ fc1w, const float* __restrict__ fc1b,
    const float* __restrict__ fc2w, const float* __restrict__ fc2b, float* __restrict__ out){
  __shared__ float gv[513];
  __shared__ float h1s[512];
  __shared__ float red[4];
  int bq = blockIdx.x, tid = threadIdx.x;
  for (int i = tid; i < 512; i += 256) gv[i] = graph_emb[(size_t)bq*512 + i];
  if (tid == 0) gv[512] = focal[bq];
  __syncthreads();
  for (int c = tid; c < 512; c += 256){
    float acc = fc1b[c];
    for (int k = 0; k < 513; k++) acc += gv[k] * fc1w[(size_t)k*512 + c];
    h1s[c] = fmaxf(acc, 0.f);
  }
  __syncthreads();
  float p = h1s[tid]*fc2w[tid] + h1s[tid+256]*fc2w[tid+256];
  for (int off = 32; off; off >>= 1) p += __shfl_down(p, off, 64);
  if ((tid & 63) == 0) red[tid >> 6] = p;
  __syncthreads();
  if (tid == 0){
    float s = red[0]+red[1]+red[2]+red[3] + fc2b[0];
    out[bq] = 1.f / (1.f + __expf(-s));
  }
}

// ---------------- launch ----------------
extern "C" void kernel_launch(void* const* d_in, const int* in_sizes, int n_in,
                              void* d_out, int out_size, void* d_ws, size_t ws_size,
                              hipStream_t stream){
  const int*   x     = (const int*)d_in[0];
  const int*   edge  = (const int*)d_in[1];
  const int*   srcp  = edge;
  const int*   dstp  = edge + EDGES;
  const float* focal = (const float*)d_in[3];
  const float* emb   = (const float*)d_in[4];
  const float* W1    = (const float*)d_in[5];
  const float* b1    = (const float*)d_in[6];
  const float* W2    = (const float*)d_in[7];
  const float* b2    = (const float*)d_in[8];
  const float* Wih   = (const float*)d_in[9];
  const float* Whh   = (const float*)d_in[10];
  const float* bih   = (const float*)d_in[11];
  const float* bhh   = (const float*)d_in[12];
  const float* fc1w  = (const float*)d_in[13];
  const float* fc1b  = (const float*)d_in[14];
  const float* fc2w  = (const float*)d_in[15];
  const float* fc2b  = (const float*)d_in[16];

  char* ws = (char*)d_ws;
  constexpr size_t H2_OFF    = 0;                      // 32 MB
  constexpr size_t AGG1_OFF  = 33554432;               // 16 MB
  constexpr size_t H1_OFF    = 50331648;               // 32 MB
  constexpr size_t AGG2_OFF  = 83886080;               // 32 MB
  constexpr size_t GI_OFF    = 33554432;               // 96 MB (after aggs dead)
  constexpr size_t MISC      = 134217728;
  constexpr size_t INDEG_OFF = MISC;
  constexpr size_t CNT_OFF   = MISC + 131072;
  constexpr size_t DINV_OFF  = MISC + 131328;
  constexpr size_t ROWPTR_OFF= MISC + 262400;
  constexpr size_t CURSOR_OFF= MISC + 393472;
  constexpr size_t CSR_OFF   = MISC + 524544;
  constexpr size_t W1T_OFF   = MISC + 2621696;
  constexpr size_t W2T_OFF   = MISC + 2883840;
  constexpr size_t WIHB_OFF  = MISC + 3408128;
  constexpr size_t XBUF_OFF  = MISC + 4980992;
  constexpr size_t GEMB_OFF  = MISC + 5112064;

  int*   indeg  = (int*)(ws + INDEG_OFF);
  int*   cntp   = (int*)(ws + CNT_OFF);
  float* dinv   = (float*)(ws + DINV_OFF);
  int*   rowptr = (int*)(ws + ROWPTR_OFF);
  int*   cursor = (int*)(ws + CURSOR_OFF);
  int*   csrsrc = (int*)(ws + CSR_OFF);
  u16*   W1T    = (u16*)(ws + W1T_OFF);
  u16*   W2T    = (u16*)(ws + W2T_OFF);
  u16*   WihB   = (u16*)(ws + WIHB_OFF);
  u16*   agg1   = (u16*)(ws + AGG1_OFF);
  u16*   h1     = (u16*)(ws + H1_OFF);
  u16*   agg2   = (u16*)(ws + AGG2_OFF);
  u16*   h2     = (u16*)(ws + H2_OFF);
  u16*   gi     = (u16*)(ws + GI_OFF);
  u16*   xbuf   = (u16*)(ws + XBUF_OFF);
  float* gemb   = (float*)(ws + GEMB_OFF);

  zero_i32<<<129, 256, 0, stream>>>(indeg, 32768 + 64);   // indeg + cnt
  transpose_cast<<<512, 256, 0, stream>>>(W1, W1T, 256, 512);
  transpose_cast<<<1024, 256, 0, stream>>>(W2, W2T, 512, 512);
  cast_bf<<<3072, 256, 0, stream>>>(Wih, WihB, 1536*512);
  count_indeg<<<2048, 256, 0, stream>>>(dstp, indeg);
  compute_dinv<<<128, 256, 0, stream>>>(indeg, dinv);
  scan_csr<<<1, 1024, 0, stream>>>(indeg, rowptr, cursor);
  fill_csr<<<2048, 256, 0, stream>>>(srcp, dstp, cursor, csrsrc);
  agg_emb<<<8192, 256, 0, stream>>>(x, emb, dinv, rowptr, indeg, csrsrc, agg1);
  gemm_bt<<<dim3(4, 256), 256, 0, stream>>>(agg1, W1T, b1, h1, NODES, 512, 256, 1);
  agg_h<<<8192, 256, 0, stream>>>(h1, dinv, rowptr, indeg, csrsrc, agg2);
  gemm_bt<<<dim3(4, 256), 256, 0, stream>>>(agg2, W2T, b2, h2, NODES, 512, 512, 1);
  gemm_bt<<<dim3(12, 256), 256, 0, stream>>>(h2, WihB, bih, gi, NODES, 1536, 512, 0);
  gru_kernel<<<64, 512, 0, stream>>>(gi, Whh, bhh, gemb, xbuf, cntp);
  head<<<64, 256, 0, stream>>>(gemb, focal, fc1w, fc1b, fc2w, fc2b, (float*)d_out);
}

// Round 5
// 2587.240 us; speedup vs baseline: 4.4692x; 1.0604x over previous
//
#include <hip/hip_runtime.h>

#define NODES 32768
#define EDGES 524288
#define BGR   64
#define LSEQ  512
#define DEMB  256
#define HDIM  512

typedef unsigned short u16;
typedef unsigned int   u32;
typedef unsigned long long u64;
typedef __attribute__((ext_vector_type(8))) short short8;
typedef __attribute__((ext_vector_type(4))) float f32x4;

__device__ __forceinline__ float bf2f(u16 u){ u32 x = ((u32)u)<<16; float f; __builtin_memcpy(&f,&x,4); return f; }
__device__ __forceinline__ u16 f2bf(float f){ u32 x; __builtin_memcpy(&x,&f,4); u32 r = x + 0x7fffu + ((x>>16)&1u); return (u16)(r>>16); }
__device__ __forceinline__ float lo16(u32 u){ u32 x = u<<16; float f; __builtin_memcpy(&f,&x,4); return f; }
__device__ __forceinline__ float hi16(u32 u){ u32 x = u & 0xffff0000u; float f; __builtin_memcpy(&f,&x,4); return f; }
__device__ __forceinline__ u32 pack2(float a, float b){ return (u32)f2bf(a) | ((u32)f2bf(b)<<16); }

// ---------------- utility kernels ----------------

__global__ void zero_i32(int* p, int n){
  int i = blockIdx.x*256 + threadIdx.x;
  if (i < n) p[i] = 0;
}

// out[n*K + k] = bf16(in[k*N + n])   (in is [K][N] row-major)
__global__ void transpose_cast(const float* __restrict__ in, u16* __restrict__ out, int K, int N){
  int i = blockIdx.x*256 + threadIdx.x;
  if (i < N*K){ int n = i / K, k = i - n*K; out[i] = f2bf(in[(size_t)k*N + n]); }
}

__global__ void cast_bf(const float* __restrict__ in, u16* __restrict__ out, int n){
  int i = blockIdx.x*256 + threadIdx.x;
  if (i < n) out[i] = f2bf(in[i]);
}

__global__ void count_indeg(const int* __restrict__ dst, int* __restrict__ indeg){
  int e = blockIdx.x*256 + threadIdx.x;
  if (e < EDGES) atomicAdd(&indeg[dst[e]], 1);
}

__global__ void compute_dinv(const int* __restrict__ indeg, float* __restrict__ dinv){
  int i = blockIdx.x*256 + threadIdx.x;
  if (i < NODES) dinv[i] = rsqrtf((float)(indeg[i] + 1));  // +1 self loop
}

// single-block exclusive scan of indeg -> row_ptr (+cursor copy). N = 32768 = 1024*32
__global__ __launch_bounds__(1024) void scan_csr(const int* __restrict__ indeg,
                                                 int* __restrict__ row_ptr,
                                                 int* __restrict__ cursor){
  __shared__ int part[1024];
  int tid = threadIdx.x, base = tid*32;
  int loc[32]; int s = 0;
  for (int i=0;i<32;i++){ loc[i] = s; s += indeg[base+i]; }
  part[tid] = s; __syncthreads();
  for (int off=1; off<1024; off<<=1){
    int v = part[tid]; int add = (tid>=off) ? part[tid-off] : 0;
    __syncthreads(); part[tid] = v + add; __syncthreads();
  }
  int offt = (tid==0) ? 0 : part[tid-1];
  for (int i=0;i<32;i++){ int v = offt + loc[i]; row_ptr[base+i] = v; cursor[base+i] = v; }
}

__global__ void fill_csr(const int* __restrict__ src, const int* __restrict__ dst,
                         int* __restrict__ cursor, int* __restrict__ csr_src){
  int e = blockIdx.x*256 + threadIdx.x;
  if (e < EDGES){ int d = dst[e]; int p = atomicAdd(&cursor[d], 1); csr_src[p] = src[e]; }
}

// ---------------- GCN aggregation ----------------
// bf16 embedding table (precast): halves gather traffic, ~fits XCD L2.
__global__ __launch_bounds__(256) void agg_emb(const int* __restrict__ x, const u16* __restrict__ embb,
    const float* __restrict__ dinv, const int* __restrict__ row_ptr, const int* __restrict__ indeg,
    const int* __restrict__ csr_src, u16* __restrict__ out){
  int node = blockIdx.x*4 + (threadIdx.x>>6);
  int lane = threadIdx.x & 63;
  float di = dinv[node];
  int xi = x[node];
  u64 hv = *(const u64*)(embb + (size_t)xi*DEMB + lane*4);
  u32 h0 = (u32)hv, h1 = (u32)(hv>>32);
  float a0 = lo16(h0)*di, a1 = hi16(h0)*di, a2 = lo16(h1)*di, a3 = hi16(h1)*di;
  int st = row_ptr[node], cn = indeg[node];
  for (int p = st; p < st+cn; p++){
    int s = csr_src[p];
    float ws = dinv[s];
    u64 v = *(const u64*)(embb + (size_t)x[s]*DEMB + lane*4);
    u32 w0 = (u32)v, w1 = (u32)(v>>32);
    a0 += lo16(w0)*ws; a1 += hi16(w0)*ws; a2 += lo16(w1)*ws; a3 += hi16(w1)*ws;
  }
  u64 pv = (u64)pack2(a0*di,a1*di) | ((u64)pack2(a2*di,a3*di)<<32);
  *(u64*)(out + (size_t)node*DEMB + lane*4) = pv;
}

__global__ __launch_bounds__(256) void agg_h(const u16* __restrict__ hin, const float* __restrict__ dinv,
    const int* __restrict__ row_ptr, const int* __restrict__ indeg,
    const int* __restrict__ csr_src, u16* __restrict__ out){
  int node = blockIdx.x*4 + (threadIdx.x>>6);
  int lane = threadIdx.x & 63;
  float di = dinv[node];
  float a[8];
  uint4 hv = *((const uint4*)(hin + (size_t)node*HDIM) + lane);
  a[0]=lo16(hv.x)*di; a[1]=hi16(hv.x)*di; a[2]=lo16(hv.y)*di; a[3]=hi16(hv.y)*di;
  a[4]=lo16(hv.z)*di; a[5]=hi16(hv.z)*di; a[6]=lo16(hv.w)*di; a[7]=hi16(hv.w)*di;
  int st = row_ptr[node], cn = indeg[node];
  for (int p = st; p < st+cn; p++){
    int s = csr_src[p];
    float ws = dinv[s];
    uint4 v = *((const uint4*)(hin + (size_t)s*HDIM) + lane);
    a[0]+=lo16(v.x)*ws; a[1]+=hi16(v.x)*ws; a[2]+=lo16(v.y)*ws; a[3]+=hi16(v.y)*ws;
    a[4]+=lo16(v.z)*ws; a[5]+=hi16(v.z)*ws; a[6]+=lo16(v.w)*ws; a[7]+=hi16(v.w)*ws;
  }
  uint4 o; o.x=pack2(a[0]*di,a[1]*di); o.y=pack2(a[2]*di,a[3]*di);
  o.z=pack2(a[4]*di,a[5]*di); o.w=pack2(a[6]*di,a[7]*di);
  *(uint4*)(out + (size_t)node*HDIM + lane*8) = o;
}

// ---------------- bf16 MFMA GEMM: C[M,N] = act(A[M,K] @ BT[N,K]^T + bias) ----------------
#define BM 128
#define BN 128
#define BKK 32
__global__ __launch_bounds__(256) void gemm_bt(const u16* __restrict__ A, const u16* __restrict__ BT,
    const float* __restrict__ bias, u16* __restrict__ C, int M, int N, int K, int relu){
  __shared__ u16 aS[BM][BKK+8];
  __shared__ u16 bS[BN][BKK+8];
  int tid = threadIdx.x;
  int m0 = blockIdx.y * BM, n0 = blockIdx.x * BN;
  int lane = tid & 63, w = tid >> 6;
  int wm = w >> 1, wn = w & 1;
  f32x4 acc[4][4];
  for (int i=0;i<4;i++) for (int j=0;j<4;j++) acc[i][j] = (f32x4)0.0f;

  int r  = tid >> 1;
  int cc = (tid & 1) * 16;
  const u16* Ag = A + (size_t)(m0 + r) * K + cc;
  const u16* Bg = BT + (size_t)(n0 + r) * K + cc;
  int l15 = lane & 15, q8 = (lane >> 4) * 8;

  for (int k0 = 0; k0 < K; k0 += BKK) {
    uint4 av0 = *(const uint4*)(Ag + k0);
    uint4 av1 = *(const uint4*)(Ag + k0 + 8);
    uint4 bv0 = *(const uint4*)(Bg + k0);
    uint4 bv1 = *(const uint4*)(Bg + k0 + 8);
    *(uint4*)&aS[r][cc]   = av0; *(uint4*)&aS[r][cc+8] = av1;
    *(uint4*)&bS[r][cc]   = bv0; *(uint4*)&bS[r][cc+8] = bv1;
    __syncthreads();
    short8 af[4], bfr[4];
    for (int i=0;i<4;i++) af[i]  = *(const short8*)&aS[wm*64 + i*16 + l15][q8];
    for (int j=0;j<4;j++) bfr[j] = *(const short8*)&bS[wn*64 + j*16 + l15][q8];
    for (int i=0;i<4;i++)
      for (int j=0;j<4;j++)
        acc[i][j] = __builtin_amdgcn_mfma_f32_16x16x32_bf16(af[i], bfr[j], acc[i][j], 0, 0, 0);
    __syncthreads();
  }
  int q = lane >> 4;
  for (int i=0;i<4;i++) for (int j=0;j<4;j++){
    int col = n0 + wn*64 + j*16 + l15;
    float bval = bias[col];
    for (int rr=0; rr<4; rr++){
      int row = m0 + wm*64 + i*16 + q*4 + rr;
      float v = acc[i][j][rr] + bval;
      if (relu) v = fmaxf(v, 0.f);
      C[(size_t)row * N + col] = f2bf(v);
    }
  }
}

// ---------------- GRU: 4 groups x 16 WGs; WG j owns 32-wide H-slice (96 Whh rows LDS-resident) ----------------
// R5 sync protocol: tag-in-data, agent-scope (guaranteed visible at coherence point; R4's
// XCD/L2 scheme hung and is abandoned). Each h-pair published as u64 ((t+1)<<32 | bf16pair)
// via relaxed agent atomic store; readers poll their 8 u64 with relaxed agent atomic loads.
// Every u64 is self-validating -> no counter, no fences, no vmcnt ack: detection IS the refill.
// Skew between WGs is <=1 step (a WG publishes t+1 only after fully consuming parity t), so
// the 2-deep parity buffer is race-free. Tags 1..512 never equal 0xAAAAAAAA ws-poison.
__global__ __launch_bounds__(512) void gru_kernel(const u16* __restrict__ gi,
    const float* __restrict__ Whh, const float* __restrict__ bhh,
    float* __restrict__ graph_emb, u64* __restrict__ xbuf){
  __shared__ u16  w_lds[96*520];
  __shared__ u16  h_lds[16*520];
  __shared__ float gh_lds[16*100];

  int tid = threadIdx.x;
  int g = blockIdx.x >> 4, j = blockIdx.x & 15;
  int lane = tid & 63, wave = tid >> 6;

  // load Whh slice: rows {j*32..+32} of each gate, bf16 into LDS (padded stride 520)
  for (int idx = tid; idx < 96*512; idx += 512){
    int rr = idx >> 9, c = idx & 511;
    int grow = (rr >> 5) * 512 + j*32 + (rr & 31);
    w_lds[rr*520 + c] = f2bf(Whh[(size_t)grow*512 + c]);
  }
  for (int idx = tid; idx < 16*520; idx += 512) h_lds[idx] = 0;

  int b = tid >> 5, hh = tid & 31;     // (batch-in-group, h-in-slice)
  int bg = g*16 + b;
  int c_r = j*32 + hh, c_z = 512 + j*32 + hh, c_n = 1024 + j*32 + hh;
  float bias_r = bhh[c_r], bias_z = bhh[c_z], bias_n = bhh[c_n];
  const u16* gi_row = gi + (size_t)bg * LSEQ * 1536;
  float h_prev = 0.f, accm = 0.f;
  int l15 = lane & 15, q8 = (lane>>4)*8, qr = (lane>>4)*4;

  u64* xb = xbuf + (size_t)g * 8192;   // [parity][16 b][256 slots] u64
  // pipeline: gate inputs for step t held in registers
  u16 g_r = gi_row[c_r], g_z = gi_row[c_z], g_n = gi_row[c_n];

  __syncthreads();

  for (int t = 0; t < LSEQ; t++){
    if (wave < 6){
      f32x4 acc0 = (f32x4)0.0f, acc1 = (f32x4)0.0f;
      const u16* wrow = &w_lds[(wave*16 + l15)*520];
      const u16* hrow = &h_lds[l15*520];
      #pragma unroll
      for (int k0 = 0; k0 < 256; k0 += 32){
        acc0 = __builtin_amdgcn_mfma_f32_16x16x32_bf16(*(const short8*)(hrow + k0 + q8),
                                                       *(const short8*)(wrow + k0 + q8), acc0, 0, 0, 0);
        acc1 = __builtin_amdgcn_mfma_f32_16x16x32_bf16(*(const short8*)(hrow + 256 + k0 + q8),
                                                       *(const short8*)(wrow + 256 + k0 + q8), acc1, 0, 0, 0);
      }
      f32x4 acc = acc0 + acc1;
      int col = wave*16 + l15;
      #pragma unroll
      for (int rr2 = 0; rr2 < 4; rr2++) gh_lds[(qr + rr2)*100 + col] = acc[rr2];
    }
    __syncthreads();

    float ghr = gh_lds[b*100 + hh]      + bias_r;
    float ghz = gh_lds[b*100 + 32 + hh] + bias_z;
    float ghn = gh_lds[b*100 + 64 + hh] + bias_n;
    float rg = 1.f / (1.f + __expf(-(bf2f(g_r) + ghr)));
    float zg = 1.f / (1.f + __expf(-(bf2f(g_z) + ghz)));
    float pre = bf2f(g_n) + rg * ghn;
    pre = fminf(fmaxf(pre, -20.f), 20.f);
    float e2 = __expf(2.f * pre);
    float nn = (e2 - 1.f) / (e2 + 1.f);
    float h_new = (1.f - zg) * nn + zg * h_prev;
    accm += h_new; h_prev = h_new;

    u32 tag = (u32)(t + 1);
    // publish: tagged u64, relaxed agent-scope atomic store (fire-and-forget)
    float h_nb = __shfl_xor(h_new, 1, 64);   // partner hh^1 (same wave: lane^1)
    if ((hh & 1) == 0){
      u64 val = ((u64)tag << 32) | (u64)pack2(h_new, h_nb);
      __hip_atomic_store(xb + (size_t)((t&1)*16 + b)*256 + j*16 + (hh>>1), val,
                         __ATOMIC_RELAXED, __HIP_MEMORY_SCOPE_AGENT);
    }

    // prefetch next step's gate inputs (overlaps the poll)
    int tn = (t + 1 < LSEQ) ? t + 1 : t;
    const u16* gp2 = gi_row + (size_t)tn * 1536;
    u16 n_r = gp2[c_r], n_z = gp2[c_z], n_n = gp2[c_n];

    // poll own 8 tagged u64 (64 B, covers slices hh/2 halves) — detection IS the refill
    const u64* rp = xb + (size_t)((t&1)*16 + b)*256 + hh*8;
    u64 v[8];
    bool ok;
    do {
      #pragma unroll
      for (int i=0;i<8;i++) v[i] = __hip_atomic_load(rp + i, __ATOMIC_RELAXED, __HIP_MEMORY_SCOPE_AGENT);
      ok = true;
      #pragma unroll
      for (int i=0;i<8;i++) ok = ok && ((u32)(v[i] >> 32) == tag);
    } while (!ok);

    // commit 8 pairs (32 B) into h_lds row b
    u32* hl = (u32*)h_lds + b*260 + hh*8;
    #pragma unroll
    for (int i=0;i<8;i++) hl[i] = (u32)v[i];
    __syncthreads();

    g_r = n_r; g_z = n_z; g_n = n_n;
  }
  graph_emb[(size_t)bg*512 + j*32 + hh] = accm * (1.f/512.f);
}

// ---------------- head: relu(g@fc1+b) @ fc2 + b -> sigmoid ----------------
__global__ __launch_bounds__(256) void head(const float* __restrict__ graph_emb, const float* __restrict__ focal,
    const float* __restrict__ fc1w, const float* __restrict__ fc1b,
    const float* __restrict__ fc2w, const float* __restrict__ fc2b, float* __restrict__ out){
  __shared__ float gv[513];
  __shared__ float h1s[512];
  __shared__ float red[4];
  int bq = blockIdx.x, tid = threadIdx.x;
  for (int i = tid; i < 512; i += 256) gv[i] = graph_emb[(size_t)bq*512 + i];
  if (tid == 0) gv[512] = focal[bq];
  __syncthreads();
  for (int c = tid; c < 512; c += 256){
    float acc = fc1b[c];
    for (int k = 0; k < 513; k++) acc += gv[k] * fc1w[(size_t)k*512 + c];
    h1s[c] = fmaxf(acc, 0.f);
  }
  __syncthreads();
  float p = h1s[tid]*fc2w[tid] + h1s[tid+256]*fc2w[tid+256];
  for (int off = 32; off; off >>= 1) p += __shfl_down(p, off, 64);
  if ((tid & 63) == 0) red[tid >> 6] = p;
  __syncthreads();
  if (tid == 0){
    float s = red[0]+red[1]+red[2]+red[3] + fc2b[0];
    out[bq] = 1.f / (1.f + __expf(-s));
  }
}

// ---------------- launch ----------------
extern "C" void kernel_launch(void* const* d_in, const int* in_sizes, int n_in,
                              void* d_out, int out_size, void* d_ws, size_t ws_size,
                              hipStream_t stream){
  const int*   x     = (const int*)d_in[0];
  const int*   edge  = (const int*)d_in[1];
  const int*   srcp  = edge;
  const int*   dstp  = edge + EDGES;
  const float* focal = (const float*)d_in[3];
  const float* emb   = (const float*)d_in[4];
  const float* W1    = (const float*)d_in[5];
  const float* b1    = (const float*)d_in[6];
  const float* W2    = (const float*)d_in[7];
  const float* b2    = (const float*)d_in[8];
  const float* Wih   = (const float*)d_in[9];
  const float* Whh   = (const float*)d_in[10];
  const float* bih   = (const float*)d_in[11];
  const float* bhh   = (const float*)d_in[12];
  const float* fc1w  = (const float*)d_in[13];
  const float* fc1b  = (const float*)d_in[14];
  const float* fc2w  = (const float*)d_in[15];
  const float* fc2b  = (const float*)d_in[16];

  char* ws = (char*)d_ws;
  constexpr size_t H2_OFF    = 0;                      // 32 MB
  constexpr size_t AGG1_OFF  = 33554432;               // 16 MB
  constexpr size_t H1_OFF    = 50331648;               // 32 MB
  constexpr size_t AGG2_OFF  = 83886080;               // 32 MB (embb lives here until agg_h)
  constexpr size_t GI_OFF    = 33554432;               // 96 MB (after aggs dead)
  constexpr size_t MISC      = 134217728;
  constexpr size_t INDEG_OFF = MISC;
  constexpr size_t CNT_OFF   = MISC + 131072;
  constexpr size_t DINV_OFF  = MISC + 131328;
  constexpr size_t ROWPTR_OFF= MISC + 262400;
  constexpr size_t CURSOR_OFF= MISC + 393472;
  constexpr size_t CSR_OFF   = MISC + 524544;
  constexpr size_t W1T_OFF   = MISC + 2621696;
  constexpr size_t W2T_OFF   = MISC + 2883840;
  constexpr size_t WIHB_OFF  = MISC + 3408128;
  constexpr size_t XBUF_OFF  = MISC + 4980992;         // 4 groups x 8192 u64 = 256 KB
  constexpr size_t GEMB_OFF  = MISC + 5243136;

  int*   indeg  = (int*)(ws + INDEG_OFF);
  float* dinv   = (float*)(ws + DINV_OFF);
  int*   rowptr = (int*)(ws + ROWPTR_OFF);
  int*   cursor = (int*)(ws + CURSOR_OFF);
  int*   csrsrc = (int*)(ws + CSR_OFF);
  u16*   W1T    = (u16*)(ws + W1T_OFF);
  u16*   W2T    = (u16*)(ws + W2T_OFF);
  u16*   WihB   = (u16*)(ws + WIHB_OFF);
  u16*   agg1   = (u16*)(ws + AGG1_OFF);
  u16*   h1     = (u16*)(ws + H1_OFF);
  u16*   agg2   = (u16*)(ws + AGG2_OFF);
  u16*   embb   = (u16*)(ws + AGG2_OFF);               // dead before agg_h writes agg2
  u16*   h2     = (u16*)(ws + H2_OFF);
  u16*   gi     = (u16*)(ws + GI_OFF);
  u64*   xbuf   = (u64*)(ws + XBUF_OFF);
  float* gemb   = (float*)(ws + GEMB_OFF);

  zero_i32<<<129, 256, 0, stream>>>(indeg, 32768 + 64);
  transpose_cast<<<512, 256, 0, stream>>>(W1, W1T, 256, 512);
  transpose_cast<<<1024, 256, 0, stream>>>(W2, W2T, 512, 512);
  cast_bf<<<3072, 256, 0, stream>>>(Wih, WihB, 1536*512);
  cast_bf<<<10000, 256, 0, stream>>>(emb, embb, 10000*256);
  count_indeg<<<2048, 256, 0, stream>>>(dstp, indeg);
  compute_dinv<<<128, 256, 0, stream>>>(indeg, dinv);
  scan_csr<<<1, 1024, 0, stream>>>(indeg, rowptr, cursor);
  fill_csr<<<2048, 256, 0, stream>>>(srcp, dstp, cursor, csrsrc);
  agg_emb<<<8192, 256, 0, stream>>>(x, embb, dinv, rowptr, indeg, csrsrc, agg1);
  gemm_bt<<<dim3(4, 256), 256, 0, stream>>>(agg1, W1T, b1, h1, NODES, 512, 256, 1);
  agg_h<<<8192, 256, 0, stream>>>(h1, dinv, rowptr, indeg, csrsrc, agg2);
  gemm_bt<<<dim3(4, 256), 256, 0, stream>>>(agg2, W2T, b2, h2, NODES, 512, 512, 1);
  gemm_bt<<<dim3(12, 256), 256, 0, stream>>>(h2, WihB, bih, gi, NODES, 1536, 512, 0);
  gru_kernel<<<64, 512, 0, stream>>>(gi, Whh, bhh, gemb, xbuf);
  head<<<64, 256, 0, stream>>>(gemb, focal, fc1w, fc1b, fc2w, fc2b, (float*)d_out);
}